// Round 5
// baseline (355.953 us; speedup 1.0000x reference)
//
#include <hip/hip_runtime.h>

// Shift-TCN fused pipeline, MI355X (gfx950).
// [memset acc=0]
// [K1] BN1 partial stats (atomic) + w fp32->bf16 (fused grid slice)
// [K2] BN1 param finalize (per-block, 16ch) + affine + shift_in -> h_t (bf16, K-contig)
// [K3] MFMA bf16 GEMM 128x128 tiles, flattened J=(n,tv), global_load_lds staging, +bias+relu -> y bf16
// [K4] shift_out + BN2 partial stats (atomic) — LDS-free, flat-index shift
// [K5] shift_out + BN2 affine -> out (fp32) — LDS-free, flat-index shift

#define EPSV 1e-5f
constexpr int Nn = 64, Cc = 256, Tt = 64, Vv = 25;
constexpr int TV = Tt * Vv;          // 1600
constexpr int CTV = Cc * TV;         // 409600
constexpr float Minv = 1.0f / (Nn * TV);   // 1/102400

typedef short short8 __attribute__((ext_vector_type(8)));
typedef float floatx4 __attribute__((ext_vector_type(4)));

__device__ __forceinline__ unsigned short f2bf(float f) {
    unsigned int u = __builtin_bit_cast(unsigned int, f);
    u += 0x7FFFu + ((u >> 16) & 1u);      // round-to-nearest-even
    return (unsigned short)(u >> 16);
}
__device__ __forceinline__ float bf2f(unsigned short h) {
    unsigned int u = ((unsigned int)h) << 16;
    return __builtin_bit_cast(float, u);
}
__device__ __forceinline__ void gload_lds16(const void* g, void* l) {
    __builtin_amdgcn_global_load_lds((const __attribute__((address_space(1))) void*)g,
                                     (__attribute__((address_space(3))) void*)l, 16, 0, 0);
}

// ------- K1: BN1 partial stats, grid (8, 257); y==256 slice converts conv_w -------
__global__ __launch_bounds__(256) void k_bn1_stats(const float* __restrict__ x,
                                                   const float* __restrict__ w,
                                                   unsigned short* __restrict__ wb,
                                                   float* __restrict__ sacc,
                                                   float* __restrict__ qacc) {
    int c = blockIdx.y, ng = blockIdx.x, tid = threadIdx.x;
    if (c == 256) {            // fused conv_w fp32->bf16 (65536 elems over 8 blocks)
        int base = ng * 8192 + tid;
#pragma unroll
        for (int i = 0; i < 32; ++i) wb[base + i * 256] = f2bf(w[base + i * 256]);
        return;
    }
    const float* xp = x + (size_t)(ng * 8) * CTV + (size_t)c * TV;
    float s = 0.f, q = 0.f;
    for (int n = 0; n < 8; ++n) {
        const float4* p = (const float4*)(xp + (size_t)n * CTV);
        for (int i = tid; i < 400; i += 256) {
            float4 v = p[i];
            s += (v.x + v.y) + (v.z + v.w);
            q += (v.x * v.x + v.y * v.y) + (v.z * v.z + v.w * v.w);
        }
    }
    for (int off = 32; off; off >>= 1) { s += __shfl_down(s, off); q += __shfl_down(q, off); }
    if ((tid & 63) == 0) { atomicAdd(&sacc[c], s); atomicAdd(&qacc[c], q); }
}

// ------- K2: h = shift_in(BN1(x)) -> ht[n][tv][c] bf16 (K-contig) -------
// grid (16 c-grp, 4 t-tile, 64 n). BN1 params computed in-block (16ch).
__global__ __launch_bounds__(256) void k_bn1_shift(const float* __restrict__ x,
                                                   const float* __restrict__ sacc,
                                                   const float* __restrict__ qacc,
                                                   const float* __restrict__ g,
                                                   const float* __restrict__ b,
                                                   const float* __restrict__ theta,
                                                   unsigned short* __restrict__ ht) {
    int c0 = blockIdx.x * 16;
    int tile = blockIdx.y;
    int n = blockIdx.z;
    int tid = threadIdx.x;
    __shared__ __attribute__((aligned(16))) float lds[16][460];
    __shared__ float psc[16], ptc[16], pfr[16];
    __shared__ int pdd[16], pww[16];

    if (tid < 16) {
        int c = c0 + tid;
        float mean = sacc[c] * Minv;
        float var = qacc[c] * Minv - mean * mean;
        float sc = g[c] * rsqrtf(var + EPSV);
        float th = theta[c];
        float fd = floorf(th);
        int d = (int)fd;
        pdd[tid] = d;
        pww[tid] = 28 + d * 25;
        pfr[tid] = th - fd;
        psc[tid] = sc;
        ptc[tid] = b[c] - mean * sc;
    }

    int E0 = tile * 400;
    int lo = E0 - 28; if (lo < 0) lo = 0;
    int hi = E0 + 428; if (hi > 1600) hi = 1600;
    int ldsoff = lo - (E0 - 28);         // 0 or 28 (multiple of 4)
    int nf4 = (hi - lo) >> 2;
    {
        int ci = tid >> 4, li = tid & 15;
        const float4* xrow = (const float4*)(x + (size_t)n * CTV + (size_t)(c0 + ci) * TV + lo);
        float* lrow = &lds[ci][ldsoff];
        for (int i = li; i < nf4; i += 16)
            *(float4*)(lrow + i * 4) = xrow[i];
    }
    __syncthreads();

    int oct = tid & 1, tvr = tid >> 1;
    unsigned short* outb = ht + (size_t)n * CTV + c0 + oct * 8;
    for (int tv_l = tvr; tv_l < 400; tv_l += 128) {
        int e = E0 + tv_l;
        int t = e / 25;
        unsigned int wrds[4];
#pragma unroll
        for (int k = 0; k < 8; ++k) {
            int ci = oct * 8 + k;
            int i0 = t + pdd[ci];
            int w0 = tv_l + pww[ci];
            float x0 = lds[ci][w0];
            float x1 = lds[ci][w0 + 25];
            float sc = psc[ci], tc = ptc[ci], f = pfr[ci];
            float b0 = ((unsigned)i0 < 64u) ? (x0 * sc + tc) : 0.f;
            float b1 = ((unsigned)(i0 + 1) < 64u) ? (x1 * sc + tc) : 0.f;
            unsigned short hb = f2bf(b0 + f * (b1 - b0));
            if (k & 1) wrds[k >> 1] |= ((unsigned int)hb) << 16;
            else       wrds[k >> 1] = hb;
        }
        uint4 st = { wrds[0], wrds[1], wrds[2], wrds[3] };
        *(uint4*)(outb + (size_t)e * 256) = st;
    }
}

// ------- K3: y = relu(W h + b). Flattened J GEMM, 128x128 tile, grid (800, 2) -------
__global__ __launch_bounds__(256) void k_gemm(const unsigned short* __restrict__ ht,
                                              const unsigned short* __restrict__ wb,
                                              const float* __restrict__ bias,
                                              unsigned short* __restrict__ y) {
    int j0 = blockIdx.x * 128;
    int o0 = blockIdx.y * 128;
    int tid = threadIdx.x;
    int w = tid >> 6, lane = tid & 63;
    int quad = lane >> 4, l16 = lane & 15;
    __shared__ __attribute__((aligned(16))) unsigned short A[128 * 32];
    __shared__ __attribute__((aligned(16))) unsigned short B[128 * 32];
    floatx4 acc[4][4] = {};
    int srow = w * 32 + (lane >> 2);
    int skcol = (lane & 3) * 8;
    const unsigned short* wp0 = wb + (size_t)(o0 + srow) * 256 + skcol;
    const unsigned short* hp0 = ht + (size_t)(j0 + srow) * 256 + skcol;
    int oh = w >> 1, jh = w & 1;
    for (int k0 = 0; k0 < 256; k0 += 32) {
        __syncthreads();
#pragma unroll
        for (int a = 0; a < 2; ++a) {
            gload_lds16(wp0 + (size_t)a * 16 * 256 + k0, A + (w * 32 + a * 16) * 32);
            gload_lds16(hp0 + (size_t)a * 16 * 256 + k0, B + (w * 32 + a * 16) * 32);
        }
        __syncthreads();
        short8 af[4], bf[4];
#pragma unroll
        for (int m = 0; m < 4; ++m)
            af[m] = *(const short8*)&A[(oh * 64 + m * 16 + l16) * 32 + quad * 8];
#pragma unroll
        for (int jt = 0; jt < 4; ++jt)
            bf[jt] = *(const short8*)&B[(jh * 64 + jt * 16 + l16) * 32 + quad * 8];
#pragma unroll
        for (int m = 0; m < 4; ++m)
#pragma unroll
            for (int jt = 0; jt < 4; ++jt)
                acc[m][jt] = __builtin_amdgcn_mfma_f32_16x16x32_bf16(af[m], bf[jt], acc[m][jt], 0, 0, 0);
    }
    int jbase = j0 + jh * 64;
    int n = jbase / 1600;
    int tvb = jbase - n * 1600;
    unsigned short* yb = y + (size_t)n * CTV + tvb;
#pragma unroll
    for (int m = 0; m < 4; ++m) {
        int o = o0 + oh * 64 + m * 16 + quad * 4;
#pragma unroll
        for (int r = 0; r < 4; ++r) {
            float bia = bias[o + r];
            unsigned short* yrow = yb + (size_t)(o + r) * TV;
#pragma unroll
            for (int jt = 0; jt < 4; ++jt) {
                float vv = acc[m][jt][r] + bia;
                vv = vv > 0.f ? vv : 0.f;
                yrow[jt * 16 + l16] = f2bf(vv);
            }
        }
    }
}

// ------- K4: BN2 partial stats over z = shift_out(y). grid (8 ngrp, 256 o) -------
// LDS-free: valid(i0=t+d) <=> 0 <= e+25d < 1600 (flat index), both taps coalesced.
__global__ __launch_bounds__(256) void k_bn2_stats(const unsigned short* __restrict__ y,
                                                   const float* __restrict__ theta,
                                                   float* __restrict__ sacc,
                                                   float* __restrict__ qacc) {
    int o = blockIdx.y, ng = blockIdx.x, tid = threadIdx.x;
    float th = theta[o];
    float fd = floorf(th);
    int doff = (int)fd * 25;
    float f = th - fd;
    float s = 0.f, q = 0.f;
    const unsigned short* yb = y + (size_t)(ng * 8) * CTV + (size_t)o * TV;
    for (int n = 0; n < 8; ++n) {
        const unsigned short* yp = yb + (size_t)n * CTV;
        for (int e = tid; e < 1600; e += 256) {
            int i0 = e + doff;
            float a0 = ((unsigned)i0 < 1600u) ? bf2f(yp[i0]) : 0.f;
            int i1 = i0 + 25;
            float a1 = ((unsigned)i1 < 1600u) ? bf2f(yp[i1]) : 0.f;
            float z = a0 + f * (a1 - a0);
            s += z; q += z * z;
        }
    }
    for (int off = 32; off; off >>= 1) { s += __shfl_down(s, off); q += __shfl_down(q, off); }
    if ((tid & 63) == 0) { atomicAdd(&sacc[o], s); atomicAdd(&qacc[o], q); }
}

// ------- K5: out = BN2(shift_out(y)) fp32. grid (64 n, 256 o), LDS-free -------
__global__ __launch_bounds__(256) void k_bn2_apply(const unsigned short* __restrict__ y,
                                                   const float* __restrict__ theta,
                                                   const float* __restrict__ sacc,
                                                   const float* __restrict__ qacc,
                                                   const float* __restrict__ g,
                                                   const float* __restrict__ b,
                                                   float* __restrict__ out) {
    int o = blockIdx.y, n = blockIdx.x, tid = threadIdx.x;
    float th = theta[o];
    float fd = floorf(th);
    int doff = (int)fd * 25;
    float f = th - fd;
    float mean = sacc[o] * Minv;
    float var = qacc[o] * Minv - mean * mean;
    float sc = g[o] * rsqrtf(var + EPSV);
    float tc = b[o] - mean * sc;
    const unsigned short* yp = y + (size_t)n * CTV + (size_t)o * TV;
    float4* op = (float4*)(out + (size_t)n * CTV + (size_t)o * TV);
    for (int i = tid; i < 400; i += 256) {
        float4 r;
        int e = i * 4;
#pragma unroll
        for (int k = 0; k < 4; ++k) {
            int i0 = e + k + doff;
            float a0 = ((unsigned)i0 < 1600u) ? bf2f(yp[i0]) : 0.f;
            int i1 = i0 + 25;
            float a1 = ((unsigned)i1 < 1600u) ? bf2f(yp[i1]) : 0.f;
            ((float*)&r)[k] = (a0 + f * (a1 - a0)) * sc + tc;
        }
        op[i] = r;
    }
}

extern "C" void kernel_launch(void* const* d_in, const int* in_sizes, int n_in,
                              void* d_out, int out_size, void* d_ws, size_t ws_size,
                              hipStream_t stream) {
    const float* x      = (const float*)d_in[0];
    const float* conv_w = (const float*)d_in[1];
    const float* conv_b = (const float*)d_in[2];
    const float* bn1_g  = (const float*)d_in[3];
    const float* bn1_b  = (const float*)d_in[4];
    const float* bn2_g  = (const float*)d_in[5];
    const float* bn2_b  = (const float*)d_in[6];
    const float* th_in  = (const float*)d_in[7];
    const float* th_out = (const float*)d_in[8];
    float* out = (float*)d_out;

    char* ws = (char*)d_ws;
    unsigned short* ht = (unsigned short*)ws;                   // 52,428,800 B
    unsigned short* yy = (unsigned short*)(ws + 52428800);      // 52,428,800 B
    unsigned short* wb = (unsigned short*)(ws + 104857600);     // 131,072 B
    float* sacc1 = (float*)(ws + 104988672);
    float* qacc1 = sacc1 + 256;
    float* sacc2 = qacc1 + 256;
    float* qacc2 = sacc2 + 256;

    hipMemsetAsync((void*)sacc1, 0, 4 * 256 * sizeof(float), stream);
    hipLaunchKernelGGL(k_bn1_stats, dim3(8, 257), dim3(256), 0, stream,
                       x, conv_w, wb, sacc1, qacc1);
    hipLaunchKernelGGL(k_bn1_shift, dim3(16, 4, 64), dim3(256), 0, stream,
                       x, sacc1, qacc1, bn1_g, bn1_b, th_in, ht);
    hipLaunchKernelGGL(k_gemm, dim3(800, 2), dim3(256), 0, stream, ht, wb, conv_b, yy);
    hipLaunchKernelGGL(k_bn2_stats, dim3(8, 256), dim3(256), 0, stream, yy, th_out, sacc2, qacc2);
    hipLaunchKernelGGL(k_bn2_apply, dim3(64, 256), dim3(256), 0, stream,
                       yy, th_out, sacc2, qacc2, bn2_g, bn2_b, out);
}